// Round 11
// baseline (1748.051 us; speedup 1.0000x reference)
//
#include <hip/hip_runtime.h>
#include <hip/hip_fp16.h>
#include <math.h>

namespace {

constexpr int kNN = 20000;        // real node count (src/dst < kNN)
constexpr int kN1 = 20001;        // output rows (NUM_NODES + 1)
constexpr int kNE = 1000000;      // NUM_EDGES
constexpr int kNStep = 6;
constexpr int kHid = 128;
constexpr int kB = 64;            // B_SET
constexpr int kNRel2 = 24;        // 2*NUM_REL
constexpr float kEps = 1e-10f;
constexpr int kNXcd = 8;
constexpr int kPart = 8;          // dst partitions (one per XCD)
constexpr int kPSize = 2500;      // dst nodes per partition (8*2500 = 20000)
constexpr int kKeys = kPart * kNN;              // 160000 sort keys (p, src)
constexpr int kScanBlocks = (kKeys + 255) / 256;  // 625

typedef float f32x4 __attribute__((ext_vector_type(4)));

__device__ __forceinline__ float sig(float x) { return 1.0f / (1.0f + expf(-x)); }

// ---------------- LSTM front-end ----------------

__global__ __launch_bounds__(256) void transpose_w_kernel(
    const float* __restrict__ w_ih, const float* __restrict__ w_hh,
    float* __restrict__ wt) {
  const int idx = blockIdx.x * 256 + threadIdx.x;
  if (idx < 256 * 512) {
    const int k = idx >> 9;
    const int j = idx & 511;
    wt[idx] = (k < 128) ? w_ih[j * kHid + k] : w_hh[j * kHid + (k - 128)];
  }
}

__global__ __launch_bounds__(512) void lstm_fast_kernel(
    const float* __restrict__ query_emb, const float* __restrict__ wt,
    const float* __restrict__ b_ih, const float* __restrict__ b_hh,
    const int* __restrict__ r_set, float* __restrict__ hidden /* (6,64,128) */) {
  const int b = blockIdx.x;
  const int tid = threadIdx.x;
  __shared__ float xh[256];     // [0..127]=x, [128..255]=h
  __shared__ float cst[kHid];
  __shared__ float gsm[512];
  const float bias = b_ih[tid] + b_hh[tid];
  const int q = r_set[b];
  if (tid < kHid) { cst[tid] = 0.f; xh[kHid + tid] = 0.f; }
  for (int s = 0; s < kNStep; ++s) {
    if (tid < kHid) xh[tid] = query_emb[((s < kNStep - 1) ? q : 12) * kHid + tid];
    __syncthreads();
    float acc = bias;
#pragma unroll 8
    for (int k = 0; k < 256; ++k) acc += xh[k] * wt[k * 512 + tid];
    gsm[tid] = acc;
    __syncthreads();
    if (tid < kHid) {
      const float ig = sig(gsm[tid]);
      const float fg = sig(gsm[kHid + tid]);
      const float gg = tanhf(gsm[2 * kHid + tid]);
      const float og = sig(gsm[3 * kHid + tid]);
      const float cn = fg * cst[tid] + ig * gg;
      cst[tid] = cn;
      const float hn = og * tanhf(cn);
      xh[kHid + tid] = hn;
      hidden[(s * kB + b) * kHid + tid] = hn;
    }
    __syncthreads();
  }
}

// Legacy LSTM (fallback path only).
__global__ __launch_bounds__(256) void lstm_kernel(
    const float* __restrict__ query_emb, const float* __restrict__ w_ih,
    const float* __restrict__ w_hh, const float* __restrict__ b_ih,
    const float* __restrict__ b_hh, const int* __restrict__ r_set,
    float* __restrict__ hidden) {
  const int b = blockIdx.x;
  const int tid = threadIdx.x;
  __shared__ float xs[kHid], hs[kHid], cs[kHid], gates[4 * kHid];
  if (tid < kHid) { hs[tid] = 0.f; cs[tid] = 0.f; }
  __syncthreads();
  for (int s = 0; s < kNStep; ++s) {
    const int q = (s < kNStep - 1) ? r_set[b] : 12;
    if (tid < kHid) xs[tid] = query_emb[q * kHid + tid];
    __syncthreads();
    for (int j = tid; j < 4 * kHid; j += blockDim.x) {
      const float* wi = &w_ih[j * kHid];
      const float* wh = &w_hh[j * kHid];
      float a = b_ih[j] + b_hh[j];
#pragma unroll 4
      for (int k = 0; k < kHid; ++k) a += xs[k] * wi[k] + hs[k] * wh[k];
      gates[j] = a;
    }
    __syncthreads();
    if (tid < kHid) {
      const float ig = sig(gates[tid]);
      const float fg = sig(gates[kHid + tid]);
      const float gg = tanhf(gates[2 * kHid + tid]);
      const float og = sig(gates[3 * kHid + tid]);
      const float cn = fg * cs[tid] + ig * gg;
      const float hn = og * tanhf(cn);
      cs[tid] = cn;
      hs[tid] = hn;
      hidden[(s * kB + b) * kHid + tid] = hn;
    }
    __syncthreads();
  }
}

__global__ __launch_bounds__(128) void attn_weight_kernel(
    const float* __restrict__ hidden, const float* __restrict__ wl_w,
    const float* __restrict__ wl_b, float* __restrict__ attnAll /* (6,6,64) */,
    float* __restrict__ weightAll /* (6,24,64) */) {
  const int b = blockIdx.x;
  const int tid = threadIdx.x;
  __shared__ float hsm[kNStep][kHid];
  __shared__ float G[kNStep][kNStep];
  __shared__ float logits[kNStep][kNRel2];
  for (int s = 0; s < kNStep; ++s) hsm[s][tid] = hidden[(s * kB + b) * kHid + tid];
  __syncthreads();
  if (tid < 36) {
    const int i = tid / 6, t = tid % 6;
    if (t <= i) {
      float acc = 0.f;
      for (int k = 0; k < kHid; ++k) acc += hsm[i][k] * hsm[t][k];
      G[i][t] = acc;
    }
  }
  for (int p = tid; p < kNStep * kNRel2; p += 128) {
    const int i = p / kNRel2, r = p % kNRel2;
    float acc = wl_b[r];
    for (int k = 0; k < kHid; ++k) acc += hsm[i][k] * wl_w[r * kHid + k];
    logits[i][r] = acc;
  }
  __syncthreads();
  if (tid < kNStep) {
    const int i = tid;
    float m = G[i][0];
    for (int t = 1; t <= i; ++t) m = fmaxf(m, G[i][t]);
    float ssum = 0.f;
    float ev[kNStep];
    for (int t = 0; t <= i; ++t) { ev[t] = expf(G[i][t] - m); ssum += ev[t]; }
    for (int t = 0; t <= i; ++t) attnAll[(i * kNStep + t) * kB + b] = ev[t] / ssum;
    float mw = logits[i][0];
    for (int r = 1; r < kNRel2; ++r) mw = fmaxf(mw, logits[i][r]);
    float sw = 0.f;
    float ew[kNRel2];
    for (int r = 0; r < kNRel2; ++r) { ew[r] = expf(logits[i][r] - mw); sw += ew[r]; }
    for (int r = 0; r < kNRel2; ++r) weightAll[(i * kNRel2 + r) * kB + b] = ew[r] / sw;
  }
}

// ---------------- edge preprocessing: sort by (dstPartition, src) ----------

// count3 layout: [x][p][s] -> idx = (x*kPart + p)*kNN + s. Lines hold 16
// consecutive s for one (x,p) -> only XCD x writes a given line.

__global__ __launch_bounds__(256) void zero3_kernel(int* __restrict__ count3,
                                                    float* __restrict__ colsumAll) {
  const int total = kNXcd * kPart * kNN;
  for (int i = blockIdx.x * blockDim.x + threadIdx.x; i < total;
       i += gridDim.x * blockDim.x)
    count3[i] = 0;
  if (blockIdx.x == 0 && threadIdx.x < kNStep * kB) colsumAll[threadIdx.x] = 0.f;
}

// Same grid/stride as permute3_kernel (e->block mapping must match).
__global__ __launch_bounds__(256) void hist3_kernel(const int* __restrict__ nin,
                                                    const int* __restrict__ nout,
                                                    int* __restrict__ count3) {
  const int x = blockIdx.x & (kNXcd - 1);
  for (int e = blockIdx.x * blockDim.x + threadIdx.x; e < kNE;
       e += gridDim.x * blockDim.x) {
    const int p = nout[e] / kPSize;
    atomicAdd(&count3[(x * kPart + p) * kNN + nin[e]], 1);
  }
}

__global__ __launch_bounds__(256) void scanA_kernel(const int* __restrict__ count3,
                                                    int* __restrict__ blockSum) {
  const int tid = threadIdx.x;
  const int kidx = blockIdx.x * 256 + tid;
  int tot = 0;
  if (kidx < kKeys) {
    const int p = kidx / kNN;
    const int s = kidx - p * kNN;
#pragma unroll
    for (int x = 0; x < kNXcd; ++x) tot += count3[(x * kPart + p) * kNN + s];
  }
  __shared__ int sm[256];
  sm[tid] = tot;
  __syncthreads();
  for (int off = 128; off > 0; off >>= 1) {
    if (tid < off) sm[tid] += sm[tid + off];
    __syncthreads();
  }
  if (tid == 0) blockSum[blockIdx.x] = sm[0];
}

__global__ __launch_bounds__(1024) void scanB_kernel(int* __restrict__ blockSum,
                                                     int* __restrict__ pOff) {
  const int tid = threadIdx.x;
  __shared__ int sm[1024];
  const int v = (tid < kScanBlocks) ? blockSum[tid] : 0;
  sm[tid] = v;
  __syncthreads();
  for (int off = 1; off < 1024; off <<= 1) {
    const int t = (tid >= off) ? sm[tid - off] : 0;
    __syncthreads();
    sm[tid] += t;
    __syncthreads();
  }
  if (tid < kScanBlocks) blockSum[tid] = sm[tid] - v;  // exclusive
  if (tid == 0) pOff[kPart] = kNE;
}

__global__ __launch_bounds__(256) void scanC_kernel(int* __restrict__ count3,
                                                    const int* __restrict__ blockSum,
                                                    int* __restrict__ pOff) {
  const int tid = threadIdx.x;
  const int kidx = blockIdx.x * 256 + tid;
  int tot = 0;
  int p = 0, s = 0;
  if (kidx < kKeys) {
    p = kidx / kNN;
    s = kidx - p * kNN;
#pragma unroll
    for (int x = 0; x < kNXcd; ++x) tot += count3[(x * kPart + p) * kNN + s];
  }
  __shared__ int sm[256];
  sm[tid] = tot;
  __syncthreads();
  for (int off = 1; off < 256; off <<= 1) {
    const int t = (tid >= off) ? sm[tid - off] : 0;
    __syncthreads();
    sm[tid] += t;
    __syncthreads();
  }
  if (kidx < kKeys) {
    int sub = sm[tid] - tot + blockSum[blockIdx.x];
    if (s == 0) pOff[p] = sub;
#pragma unroll
    for (int x = 0; x < kNXcd; ++x) {
      const int idx3 = (x * kPart + p) * kNN + s;
      const int c = count3[idx3];
      count3[idx3] = sub;  // becomes the cursor
      sub += c;
    }
  }
}

// packed word: src (15b) | type (5b) | dstRel (12b), dstRel = dst - p*2500.
__global__ __launch_bounds__(256) void permute3_kernel(
    const int* __restrict__ nin, const int* __restrict__ nout,
    const int* __restrict__ etype, int* __restrict__ count3,
    unsigned* __restrict__ packed) {
  const int x = blockIdx.x & (kNXcd - 1);
  for (int e = blockIdx.x * blockDim.x + threadIdx.x; e < kNE;
       e += gridDim.x * blockDim.x) {
    const int d = nout[e];
    const int p = d / kPSize;
    const int s = nin[e];
    const int pos = atomicAdd(&count3[(x * kPart + p) * kNN + s], 1);
    packed[pos] = (unsigned)s | ((unsigned)etype[e] << 15) |
                  ((unsigned)(d - p * kPSize) << 20);
  }
}

// ---------------- per-step kernels ----------------

// Writes inpH (fp16, row-major [n][64]) AND zeroes out_i (f32 [kN1][64]).
__global__ __launch_bounds__(256) void inp_half_zero_kernel(
    const float* __restrict__ attnAll, const float* __restrict__ colsumAll,
    const int* __restrict__ h_set, const float* __restrict__ outs,
    __half* __restrict__ inp, float* __restrict__ out_next, int step) {
  __shared__ float coef[kNStep][kB];
  __shared__ int hsm[kB];
  const int tid = threadIdx.x;
  for (int j = tid; j < kNStep * kB; j += 256) {
    const int t = j >> 6, b = j & 63;
    float c = 0.f;
    if (t == 0)
      c = attnAll[(step * kNStep) * kB + b];
    else if (t <= step)
      c = attnAll[(step * kNStep + t) * kB + b] /
          fmaxf(colsumAll[(t - 1) * kB + b], kEps);
    coef[t][b] = c;
  }
  if (tid < kB) hsm[tid] = h_set[tid];
  __syncthreads();
  const int total = kN1 * 16;
  for (int idx = blockIdx.x * blockDim.x + tid; idx < total;
       idx += gridDim.x * blockDim.x) {
    const int n = idx >> 4;
    const int cg = idx & 15;  // columns cg*4 .. cg*4+3
    float ax = 0.f, ay = 0.f, az = 0.f, aw = 0.f;
    for (int t = 1; t <= step; ++t) {
      const float4 ct = *reinterpret_cast<const float4*>(&coef[t][cg * 4]);
      const f32x4 o = __builtin_nontemporal_load(reinterpret_cast<const f32x4*>(
          &outs[((long long)(t - 1) * kN1 + n) * kB + cg * 4]));
      ax += ct.x * o.x; ay += ct.y * o.y; az += ct.z * o.z; aw += ct.w * o.w;
    }
    const int c0 = cg * 4;
    if (hsm[c0 + 0] == n) ax += coef[0][c0 + 0];
    if (hsm[c0 + 1] == n) ay += coef[0][c0 + 1];
    if (hsm[c0 + 2] == n) az += coef[0][c0 + 2];
    if (hsm[c0 + 3] == n) aw += coef[0][c0 + 3];
    __half2 h0 = __floats2half2_rn(ax, ay);
    __half2 h1 = __floats2half2_rn(az, aw);
    uint2 u;
    u.x = *reinterpret_cast<unsigned*>(&h0);
    u.y = *reinterpret_cast<unsigned*>(&h1);
    *reinterpret_cast<uint2*>(inp + (long long)idx * 4) = u;
    const f32x4 z = {0.f, 0.f, 0.f, 0.f};
    *reinterpret_cast<f32x4*>(out_next + (long long)idx * 4) = z;
  }
}

// Partitioned src-sorted scatter: blockIdx%8 = partition (XCD-affine).
// Reads: packed sequential; inp rows in src-runs (wave-uniform curSrc hoist,
// L1 hits). Writes: fire-and-forget f32 atomics into this partition's 640KB
// out-slice (local-L2-resident, no cross-XCD line sharing).
__global__ __launch_bounds__(256) void scatter_part_kernel(
    const __half* __restrict__ inpH, const float* __restrict__ weight /* (24,64) */,
    const unsigned* __restrict__ packed, const int* __restrict__ pOff,
    float* __restrict__ out, float* __restrict__ colsum) {
  __shared__ float wsm[kNRel2 * kB];
  __shared__ float red[4][kB];
  const int tid = threadIdx.x;
  const int lane = tid & 63;
  const int wid = tid >> 6;
  for (int j = tid; j < kNRel2 * kB; j += 256) wsm[j] = weight[j];
  __syncthreads();
  const int p = blockIdx.x & (kPart - 1);
  const int v = blockIdx.x >> 3;                 // [0, 256)
  const int wv = v * 4 + wid;                    // [0, 1024) within partition
  const int ebeg = pOff[p];
  const int eend = pOff[p + 1];
  const int cnt = eend - ebeg;
  const int len = (cnt + 1023) >> 10;
  const int s0 = ebeg + wv * len;
  const int s1 = min(s0 + len, eend);
  const int outBase = p * kPSize * kB;
  float csum = 0.f;
  int curSrc = -1;
  float inv = 0.f;
  for (int e = s0; e < s1; ++e) {
    const unsigned u = packed[e];
    const int src = (int)(u & 0x7fffu);
    if (src != curSrc) {                          // wave-uniform branch
      curSrc = src;
      inv = __half2float(inpH[src * kB + lane]);
    }
    const float vw = inv * wsm[((u >> 15) & 31u) * kB + lane];
    unsafeAtomicAdd(&out[outBase + (int)(u >> 20) * kB + lane], vw);
    csum += vw;
  }
  red[wid][lane] = csum;
  __syncthreads();
  if (wid == 0) {
    const float r = red[0][lane] + red[1][lane] + red[2][lane] + red[3][lane];
    unsafeAtomicAdd(&colsum[lane], r);
  }
}

__global__ __launch_bounds__(256) void score_kernel(
    const float* __restrict__ outLast, const float* __restrict__ colsumLast,
    const int* __restrict__ t_index, const int* __restrict__ hr_inverse,
    const float* __restrict__ lin_w, const float* __restrict__ lin_b,
    float* __restrict__ out, int n) {
  const int i = blockIdx.x * blockDim.x + threadIdx.x;
  if (i < n) {
    const int node = t_index[i];
    const int b = hr_inverse[i];
    const float v = outLast[(long long)node * kB + b] / fmaxf(colsumLast[b], kEps);
    out[i] = v * lin_w[0] + lin_b[0];
  }
}

// ---------------- fallback (row-major float-atomic scatter) ----------------

__global__ __launch_bounds__(256) void inp_zero_kernel(
    const float* __restrict__ attnAll, const int* __restrict__ h_set,
    const float* __restrict__ outs, float* __restrict__ inp,
    float* __restrict__ out_next, float* __restrict__ colsum, int step) {
  const long long total = (long long)kN1 * kB;
  for (long long idx = (long long)blockIdx.x * blockDim.x + threadIdx.x; idx < total;
       idx += (long long)gridDim.x * blockDim.x) {
    const int b = (int)(idx & 63);
    const int n = (int)(idx >> 6);
    float acc = (h_set[b] == n) ? attnAll[(step * kNStep) * kB + b] : 0.f;
    for (int t = 1; t <= step; ++t)
      acc += attnAll[(step * kNStep + t) * kB + b] *
             outs[(long long)(t - 1) * kN1 * kB + idx];
    inp[idx] = acc;
    out_next[idx] = 0.f;
  }
  if (blockIdx.x == 0 && threadIdx.x < kB) colsum[threadIdx.x] = 0.f;
}

__global__ __launch_bounds__(256) void scatter_kernel(
    const float* __restrict__ inp, const float* __restrict__ weight,
    const int* __restrict__ nin, const int* __restrict__ nout,
    const int* __restrict__ etype, float* __restrict__ out,
    float* __restrict__ colsum) {
  const int lane = threadIdx.x & 63;
  const int wave = blockIdx.x * (blockDim.x >> 6) + (threadIdx.x >> 6);
  const int nwave = gridDim.x * (blockDim.x >> 6);
  __shared__ float wsm[kNRel2 * kB];
  for (int j = threadIdx.x; j < kNRel2 * kB; j += blockDim.x) wsm[j] = weight[j];
  __syncthreads();
  float csum = 0.f;
  for (int e = wave; e < kNE; e += nwave) {
    const float v = inp[(long long)nin[e] * kB + lane] * wsm[etype[e] * kB + lane];
    unsafeAtomicAdd(&out[(long long)nout[e] * kB + lane], v);
    csum += v;
  }
  unsafeAtomicAdd(&colsum[lane], csum);
}

__global__ __launch_bounds__(256) void normalize_kernel(
    float* __restrict__ out, const float* __restrict__ colsum) {
  const long long total = (long long)kN1 * kB;
  for (long long idx = (long long)blockIdx.x * blockDim.x + threadIdx.x; idx < total;
       idx += (long long)gridDim.x * blockDim.x)
    out[idx] /= fmaxf(colsum[idx & 63], kEps);
}

__global__ __launch_bounds__(256) void score_kernel_norm(
    const float* __restrict__ outLast, const int* __restrict__ t_index,
    const int* __restrict__ hr_inverse, const float* __restrict__ lin_w,
    const float* __restrict__ lin_b, float* __restrict__ out, int n) {
  const int i = blockIdx.x * blockDim.x + threadIdx.x;
  if (i < n) {
    out[i] = outLast[(long long)t_index[i] * kB + hr_inverse[i]] * lin_w[0] + lin_b[0];
  }
}

}  // namespace

extern "C" void kernel_launch(void* const* d_in, const int* in_sizes, int n_in,
                              void* d_out, int out_size, void* d_ws, size_t ws_size,
                              hipStream_t stream) {
  const float* query_emb = (const float*)d_in[0];
  const float* w_ih = (const float*)d_in[1];
  const float* w_hh = (const float*)d_in[2];
  const float* b_ih = (const float*)d_in[3];
  const float* b_hh = (const float*)d_in[4];
  const float* wl_w = (const float*)d_in[5];
  const float* wl_b = (const float*)d_in[6];
  const float* lin_w = (const float*)d_in[7];
  const float* lin_b = (const float*)d_in[8];
  const int* edge_index = (const int*)d_in[9];
  const int* edge_type = (const int*)d_in[10];
  const int* h_set = (const int*)d_in[11];
  const int* r_set = (const int*)d_in[12];
  const int* t_index = (const int*)d_in[13];
  const int* hr_inverse = (const int*)d_in[14];
  float* out = (float*)d_out;

  const int* nin = edge_index;
  const int* nout = edge_index + kNE;

  // ---- workspace layout ----
  float* ws = (float*)d_ws;
  float* hidden = ws;                                   // 6*64*128
  float* attnAll = hidden + kNStep * kB * kHid;         // 6*6*64
  float* weightAll = attnAll + kNStep * kNStep * kB;    // 6*24*64
  float* colsumAll = weightAll + kNStep * kNRel2 * kB;  // 6*64
  float* inpRegion = colsumAll + kNStep * kB;           // kN1*64 f32
  __half* inpH = (__half*)inpRegion;                    // [kN1][64] fp16 view
  float* outs = inpRegion + (long long)kN1 * kB;        // 6*kN1*64
  // count3 (1.28M ints = 5.12MB) OVERLAYS outs step-5 (5.125MB): its lifetime
  // (zero3..permute3) ends before step 0; outs_5 is written only at step 5.
  int* count3 = (int*)(outs + 5LL * kN1 * kB);
  float* tail = outs + (long long)kNStep * kN1 * kB;
  int* blockSum = (int*)tail;                           // kScanBlocks (<=1024)
  int* pOff = blockSum + 1024;                          // kPart+1
  unsigned* packed = (unsigned*)(pOff + 16);            // kNE
  float* wt = (float*)(packed + kNE);                   // 256*512
  const size_t needed = (size_t)((char*)(wt + 256 * 512) - (char*)d_ws);

  if (ws_size >= needed) {
    transpose_w_kernel<<<512, 256, 0, stream>>>(w_ih, w_hh, wt);
    lstm_fast_kernel<<<kB, 512, 0, stream>>>(query_emb, wt, b_ih, b_hh, r_set, hidden);
    attn_weight_kernel<<<kB, 128, 0, stream>>>(hidden, wl_w, wl_b, attnAll, weightAll);

    zero3_kernel<<<2048, 256, 0, stream>>>(count3, colsumAll);
    hist3_kernel<<<1024, 256, 0, stream>>>(nin, nout, count3);
    scanA_kernel<<<kScanBlocks, 256, 0, stream>>>(count3, blockSum);
    scanB_kernel<<<1, 1024, 0, stream>>>(blockSum, pOff);
    scanC_kernel<<<kScanBlocks, 256, 0, stream>>>(count3, blockSum, pOff);
    permute3_kernel<<<1024, 256, 0, stream>>>(nin, nout, edge_type, count3, packed);

    for (int i = 0; i < kNStep; ++i) {
      float* out_i = outs + (long long)i * kN1 * kB;
      inp_half_zero_kernel<<<1280, 256, 0, stream>>>(attnAll, colsumAll, h_set, outs,
                                                     inpH, out_i, i);
      scatter_part_kernel<<<2048, 256, 0, stream>>>(inpH,
                                                    weightAll + i * kNRel2 * kB,
                                                    packed, pOff, out_i,
                                                    colsumAll + i * kB);
    }
    score_kernel<<<(out_size + 255) / 256, 256, 0, stream>>>(
        outs + 5LL * kN1 * kB, colsumAll + 5 * kB, t_index, hr_inverse, lin_w, lin_b,
        out, out_size);
  } else {
    // ---- fallback: row-major atomic path ----
    float* inpF32 = inpRegion;
    lstm_kernel<<<kB, 256, 0, stream>>>(query_emb, w_ih, w_hh, b_ih, b_hh, r_set,
                                        hidden);
    attn_weight_kernel<<<kB, 128, 0, stream>>>(hidden, wl_w, wl_b, attnAll, weightAll);
    float* colsum = colsumAll;
    for (int i = 0; i < kNStep; ++i) {
      float* out_i = outs + (long long)i * kN1 * kB;
      inp_zero_kernel<<<2048, 256, 0, stream>>>(attnAll, h_set, outs, inpF32, out_i,
                                                colsum, i);
      scatter_kernel<<<4096, 256, 0, stream>>>(inpF32, weightAll + i * kNRel2 * kB,
                                               nin, nout, edge_type, out_i, colsum);
      normalize_kernel<<<2048, 256, 0, stream>>>(out_i, colsum);
    }
    score_kernel_norm<<<(out_size + 255) / 256, 256, 0, stream>>>(
        outs + 5LL * kN1 * kB, t_index, hr_inverse, lin_w, lin_b, out, out_size);
  }
}

// Round 12
// 613.284 us; speedup vs baseline: 2.8503x; 2.8503x over previous
//
#include <hip/hip_runtime.h>
#include <hip/hip_fp16.h>
#include <math.h>

namespace {

constexpr int kN1 = 20001;        // NUM_NODES + 1 (output rows)
constexpr int kNE = 1000000;      // NUM_EDGES
constexpr int kNStep = 6;
constexpr int kHid = 128;
constexpr int kB = 64;            // B_SET
constexpr int kNRel2 = 24;        // 2*NUM_REL
constexpr float kEps = 1e-10f;
constexpr unsigned kSent = (unsigned)kN1;     // sentinel src = zero row, etype 0
constexpr int kPMax = kNE + 8 * kN1;          // padded edge array bound
constexpr int kGatherBlocks = 2048;           // 8192 waves
constexpr int kNWaves = kGatherBlocks * 4;
constexpr int kNXcd = 8;
constexpr int kScanBlocks = (kN1 + 255) / 256;  // 79

typedef float f32x4 __attribute__((ext_vector_type(4)));
typedef unsigned u32x4 __attribute__((ext_vector_type(4)));

__device__ __forceinline__ float sig(float x) { return 1.0f / (1.0f + expf(-x)); }

__device__ __forceinline__ float2 cvt2(unsigned u) {
  __half2 h = *reinterpret_cast<__half2*>(&u);
  return __half22float2(h);
}

// ---------------- LSTM front-end ----------------

__global__ __launch_bounds__(256) void transpose_w_kernel(
    const float* __restrict__ w_ih, const float* __restrict__ w_hh,
    float* __restrict__ wt) {
  const int idx = blockIdx.x * 256 + threadIdx.x;
  if (idx < 256 * 512) {
    const int k = idx >> 9;
    const int j = idx & 511;
    wt[idx] = (k < 128) ? w_ih[j * kHid + k] : w_hh[j * kHid + (k - 128)];
  }
}

__global__ __launch_bounds__(512) void lstm_fast_kernel(
    const float* __restrict__ query_emb, const float* __restrict__ wt,
    const float* __restrict__ b_ih, const float* __restrict__ b_hh,
    const int* __restrict__ r_set, float* __restrict__ hidden /* (6,64,128) */) {
  const int b = blockIdx.x;
  const int tid = threadIdx.x;
  __shared__ float xh[256];     // [0..127]=x, [128..255]=h
  __shared__ float cst[kHid];
  __shared__ float gsm[512];
  const float bias = b_ih[tid] + b_hh[tid];
  const int q = r_set[b];
  if (tid < kHid) { cst[tid] = 0.f; xh[kHid + tid] = 0.f; }
  for (int s = 0; s < kNStep; ++s) {
    if (tid < kHid) xh[tid] = query_emb[((s < kNStep - 1) ? q : 12) * kHid + tid];
    __syncthreads();
    float acc = bias;
#pragma unroll 8
    for (int k = 0; k < 256; ++k) acc += xh[k] * wt[k * 512 + tid];
    gsm[tid] = acc;
    __syncthreads();
    if (tid < kHid) {
      const float ig = sig(gsm[tid]);
      const float fg = sig(gsm[kHid + tid]);
      const float gg = tanhf(gsm[2 * kHid + tid]);
      const float og = sig(gsm[3 * kHid + tid]);
      const float cn = fg * cst[tid] + ig * gg;
      cst[tid] = cn;
      const float hn = og * tanhf(cn);
      xh[kHid + tid] = hn;
      hidden[(s * kB + b) * kHid + tid] = hn;
    }
    __syncthreads();
  }
}

// Legacy LSTM (fallback path only).
__global__ __launch_bounds__(256) void lstm_kernel(
    const float* __restrict__ query_emb, const float* __restrict__ w_ih,
    const float* __restrict__ w_hh, const float* __restrict__ b_ih,
    const float* __restrict__ b_hh, const int* __restrict__ r_set,
    float* __restrict__ hidden) {
  const int b = blockIdx.x;
  const int tid = threadIdx.x;
  __shared__ float xs[kHid], hs[kHid], cs[kHid], gates[4 * kHid];
  if (tid < kHid) { hs[tid] = 0.f; cs[tid] = 0.f; }
  __syncthreads();
  for (int s = 0; s < kNStep; ++s) {
    const int q = (s < kNStep - 1) ? r_set[b] : 12;
    if (tid < kHid) xs[tid] = query_emb[q * kHid + tid];
    __syncthreads();
    for (int j = tid; j < 4 * kHid; j += blockDim.x) {
      const float* wi = &w_ih[j * kHid];
      const float* wh = &w_hh[j * kHid];
      float a = b_ih[j] + b_hh[j];
#pragma unroll 4
      for (int k = 0; k < kHid; ++k) a += xs[k] * wi[k] + hs[k] * wh[k];
      gates[j] = a;
    }
    __syncthreads();
    if (tid < kHid) {
      const float ig = sig(gates[tid]);
      const float fg = sig(gates[kHid + tid]);
      const float gg = tanhf(gates[2 * kHid + tid]);
      const float og = sig(gates[3 * kHid + tid]);
      const float cn = fg * cs[tid] + ig * gg;
      const float hn = og * tanhf(cn);
      cs[tid] = cn;
      hs[tid] = hn;
      hidden[(s * kB + b) * kHid + tid] = hn;
    }
    __syncthreads();
  }
}

__global__ __launch_bounds__(128) void attn_weight_kernel(
    const float* __restrict__ hidden, const float* __restrict__ wl_w,
    const float* __restrict__ wl_b, float* __restrict__ attnAll /* (6,6,64) */,
    float* __restrict__ weightAll /* (6,24,64) */) {
  const int b = blockIdx.x;
  const int tid = threadIdx.x;
  __shared__ float hsm[kNStep][kHid];
  __shared__ float G[kNStep][kNStep];
  __shared__ float logits[kNStep][kNRel2];
  for (int s = 0; s < kNStep; ++s) hsm[s][tid] = hidden[(s * kB + b) * kHid + tid];
  __syncthreads();
  if (tid < 36) {
    const int i = tid / 6, t = tid % 6;
    if (t <= i) {
      float acc = 0.f;
      for (int k = 0; k < kHid; ++k) acc += hsm[i][k] * hsm[t][k];
      G[i][t] = acc;
    }
  }
  for (int p = tid; p < kNStep * kNRel2; p += 128) {
    const int i = p / kNRel2, r = p % kNRel2;
    float acc = wl_b[r];
    for (int k = 0; k < kHid; ++k) acc += hsm[i][k] * wl_w[r * kHid + k];
    logits[i][r] = acc;
  }
  __syncthreads();
  if (tid < kNStep) {
    const int i = tid;
    float m = G[i][0];
    for (int t = 1; t <= i; ++t) m = fmaxf(m, G[i][t]);
    float ssum = 0.f;
    float ev[kNStep];
    for (int t = 0; t <= i; ++t) { ev[t] = expf(G[i][t] - m); ssum += ev[t]; }
    for (int t = 0; t <= i; ++t) attnAll[(i * kNStep + t) * kB + b] = ev[t] / ssum;
    float mw = logits[i][0];
    for (int r = 1; r < kNRel2; ++r) mw = fmaxf(mw, logits[i][r]);
    float sw = 0.f;
    float ew[kNRel2];
    for (int r = 0; r < kNRel2; ++r) { ew[r] = expf(logits[i][r] - mw); sw += ew[r]; }
    for (int r = 0; r < kNRel2; ++r) weightAll[(i * kNRel2 + r) * kB + b] = ew[r] / sw;
  }
}

// ---------------- edge preprocessing (once per launch) ----------------

__global__ __launch_bounds__(256) void zero_kernel(int* __restrict__ count2,
                                                   float* __restrict__ colsumAll) {
  const int i = blockIdx.x * blockDim.x + threadIdx.x;
  if (i < kN1 * kNXcd) count2[i] = 0;
  if (i < kNStep * kB) colsumAll[i] = 0.f;
}

// Per-(node, xcd) histogram. MUST use the same grid/stride as permute_kernel.
__global__ __launch_bounds__(256) void hist2_kernel(const int* __restrict__ nout,
                                                    int* __restrict__ count2) {
  const int xcd = blockIdx.x & (kNXcd - 1);
  for (int e = blockIdx.x * blockDim.x + threadIdx.x; e < kNE;
       e += gridDim.x * blockDim.x)
    atomicAdd(&count2[nout[e] * kNXcd + xcd], 1);
}

// Scan phase A: per-node totals + per-block padded sums (79 blocks).
__global__ __launch_bounds__(256) void scanA_kernel(const int* __restrict__ count2,
                                                    int* __restrict__ counts,
                                                    int* __restrict__ blockSum) {
  const int tid = threadIdx.x;
  const int n = blockIdx.x * 256 + tid;
  int padded = 0;
  if (n < kN1) {
    int c = 0;
#pragma unroll
    for (int x = 0; x < kNXcd; ++x) c += count2[n * kNXcd + x];
    counts[n] = c;
    padded = (c + 7) & ~7;
  }
  __shared__ int sm[256];
  sm[tid] = padded;
  __syncthreads();
  for (int off = 128; off > 0; off >>= 1) {
    if (tid < off) sm[tid] += sm[tid + off];
    __syncthreads();
  }
  if (tid == 0) blockSum[blockIdx.x] = sm[0];
}

// Scan phase B: exclusive scan of the 79 block sums (1 block, 128 threads).
__global__ __launch_bounds__(128) void scanB_kernel(int* __restrict__ blockSum) {
  const int tid = threadIdx.x;
  __shared__ int sm[128];
  const int v = (tid < kScanBlocks) ? blockSum[tid] : 0;
  sm[tid] = v;
  __syncthreads();
  for (int off = 1; off < 128; off <<= 1) {
    const int t = (tid >= off) ? sm[tid - off] : 0;
    __syncthreads();
    sm[tid] += t;
    __syncthreads();
  }
  if (tid < kScanBlocks) blockSum[tid] = sm[tid] - v;  // exclusive
}

// Scan phase C: block-local scan + write poffsets and per-(node,xcd) cursors.
__global__ __launch_bounds__(256) void scanC_kernel(const int* __restrict__ counts,
                                                    const int* __restrict__ blockSum,
                                                    int* __restrict__ count2,
                                                    int* __restrict__ poffsets) {
  const int tid = threadIdx.x;
  const int n = blockIdx.x * 256 + tid;
  const int padded = (n < kN1) ? ((counts[n] + 7) & ~7) : 0;
  __shared__ int sm[256];
  sm[tid] = padded;
  __syncthreads();
  for (int off = 1; off < 256; off <<= 1) {
    const int t = (tid >= off) ? sm[tid - off] : 0;
    __syncthreads();
    sm[tid] += t;
    __syncthreads();
  }
  const int excl = sm[tid] - padded + blockSum[blockIdx.x];
  if (n < kN1) {
    poffsets[n] = excl;
    int sub = excl;
#pragma unroll
    for (int x = 0; x < kNXcd; ++x) {
      const int c = count2[n * kNXcd + x];
      count2[n * kNXcd + x] = sub;  // becomes the cursor
      sub += c;
    }
    if (n == kN1 - 1) poffsets[kN1] = excl + padded;
  }
}

// Fill ONLY the pad slots (<=7 per node) with sentinels.
__global__ __launch_bounds__(256) void pad_fill_kernel(
    const int* __restrict__ poffsets, const int* __restrict__ counts,
    unsigned* __restrict__ packed) {
  const int i = blockIdx.x * blockDim.x + threadIdx.x;
  if (i < kN1) {
    const int s = poffsets[i] + counts[i];
    const int e = poffsets[i + 1];
    for (int k = s; k < e; ++k) packed[k] = kSent;
  }
}

// Writes land in per-(node,xcd) sub-segments -> no cross-XCD false sharing.
__global__ __launch_bounds__(256) void permute_kernel(
    const int* __restrict__ nin, const int* __restrict__ nout,
    const int* __restrict__ etype, int* __restrict__ cursor2,
    unsigned* __restrict__ packed) {
  const int xcd = blockIdx.x & (kNXcd - 1);
  for (int e = blockIdx.x * blockDim.x + threadIdx.x; e < kNE;
       e += gridDim.x * blockDim.x) {
    const int d = nout[e];
    const int pos = atomicAdd(&cursor2[d * kNXcd + xcd], 1);
    packed[pos] = (unsigned)nin[e] | ((unsigned)etype[e] << 15);
  }
}

// ---------------- per-step kernels ----------------

__global__ __launch_bounds__(256) void inp_kernel(
    const float* __restrict__ attnAll, const float* __restrict__ colsumAll,
    const int* __restrict__ h_set, const float* __restrict__ outs,
    __half* __restrict__ inp, int step) {
  __shared__ float coef[kNStep][kB];
  __shared__ int hsm[kB];
  const int tid = threadIdx.x;
  for (int j = tid; j < kNStep * kB; j += 256) {
    const int t = j >> 6, b = j & 63;
    float c = 0.f;
    if (t == 0)
      c = attnAll[(step * kNStep) * kB + b];
    else if (t <= step)
      c = attnAll[(step * kNStep + t) * kB + b] /
          fmaxf(colsumAll[(t - 1) * kB + b], kEps);
    coef[t][b] = c;
  }
  if (tid < kB) hsm[tid] = h_set[tid];
  __syncthreads();
  const int total = (kN1 + 1) * 16;
  for (int idx = blockIdx.x * blockDim.x + tid; idx < total;
       idx += gridDim.x * blockDim.x) {
    const int n = idx >> 4;
    const int cg = idx & 15;  // columns cg*4 .. cg*4+3
    float ax = 0.f, ay = 0.f, az = 0.f, aw = 0.f;
    if (n < kN1) {
      for (int t = 1; t <= step; ++t) {
        const float4 ct = *reinterpret_cast<const float4*>(&coef[t][cg * 4]);
        // NT: outs streams are read-once here; keep them out of L2.
        const f32x4 o = __builtin_nontemporal_load(reinterpret_cast<const f32x4*>(
            &outs[((long long)(t - 1) * kN1 + n) * kB + cg * 4]));
        ax += ct.x * o.x; ay += ct.y * o.y; az += ct.z * o.z; aw += ct.w * o.w;
      }
      const int c0 = cg * 4;
      if (hsm[c0 + 0] == n) ax += coef[0][c0 + 0];
      if (hsm[c0 + 1] == n) ay += coef[0][c0 + 1];
      if (hsm[c0 + 2] == n) az += coef[0][c0 + 2];
      if (hsm[c0 + 3] == n) aw += coef[0][c0 + 3];
    }
    __half2 h0 = __floats2half2_rn(ax, ay);
    __half2 h1 = __floats2half2_rn(az, aw);
    uint2 u;
    u.x = *reinterpret_cast<unsigned*>(&h0);
    u.y = *reinterpret_cast<unsigned*>(&h1);
    *reinterpret_cast<uint2*>(inp + (long long)idx * 4) = u;
  }
}

// Persistent-wave segmented SpMV, depth-8 MLP: per 64-edge window ALL 8
// row-gathers are issued into named registers before any consumption. This
// is the measured practical wall (~68us): invariant under traffic, instr
// count, NT, swizzle, and MLP depth -> per-CU outstanding-miss ceiling.
__global__ __launch_bounds__(256) void gather_seg_kernel(
    const __half* __restrict__ inp /* (kN1+1, 64) */,
    const float* __restrict__ weight /* (24,64) */,
    const unsigned* __restrict__ packed, const int* __restrict__ poffsets,
    float* __restrict__ out, float* __restrict__ colsum) {
  __shared__ __align__(16) __half wsm[kNRel2 * kB];
  __shared__ float red[4][kB];
  const int tid = threadIdx.x;
  const int lane = tid & 63;
  const int wid = tid >> 6;
  const int g = lane >> 3;   // edge slot within 8-edge group
  const int cb = lane & 7;   // 8-column (16B) block
  // XCD-bijective swizzle: XCD x owns contiguous virtual blocks.
  const int vb = (blockIdx.x & (kNXcd - 1)) * (kGatherBlocks / kNXcd) +
                 (blockIdx.x >> 3);
  for (int j = tid; j < kNRel2 * kB; j += 256) wsm[j] = __float2half(weight[j]);
  __syncthreads();

  float csum[8] = {0.f, 0.f, 0.f, 0.f, 0.f, 0.f, 0.f, 0.f};
  float acc[8] = {0.f, 0.f, 0.f, 0.f, 0.f, 0.f, 0.f, 0.f};

  auto flushNode = [&](int node) {
#pragma unroll
    for (int j = 0; j < 8; ++j) {
      acc[j] += __shfl_xor(acc[j], 8);
      acc[j] += __shfl_xor(acc[j], 16);
      acc[j] += __shfl_xor(acc[j], 32);
    }
    if (g == 0) {
      const f32x4 o0 = {acc[0], acc[1], acc[2], acc[3]};
      const f32x4 o1 = {acc[4], acc[5], acc[6], acc[7]};
      __builtin_nontemporal_store(
          o0, reinterpret_cast<f32x4*>(out + (long long)node * kB + cb * 8));
      __builtin_nontemporal_store(
          o1, reinterpret_cast<f32x4*>(out + (long long)node * kB + cb * 8 + 4));
#pragma unroll
      for (int j = 0; j < 8; ++j) csum[j] += acc[j];
    }
#pragma unroll
    for (int j = 0; j < 8; ++j) acc[j] = 0.f;
  };

  const int wave = vb * 4 + wid;
  const int P = poffsets[kN1];
  const int nG = P >> 3;
  const int chunkG = (nG + kNWaves - 1) / kNWaves;
  const int gbeg = wave * chunkG;
  if (gbeg < nG) {
    const int gend = min(gbeg + chunkG, nG);
    auto lb = [&](int x) {
      int lo = 0, hi = kN1;
      while (lo < hi) {
        const int mid = (lo + hi) >> 1;
        if (poffsets[mid] < x) lo = mid + 1; else hi = mid;
      }
      return lo;
    };
    const int nbeg = lb(gbeg * 8);
    const int nend = (gend >= nG) ? kN1 : lb(gend * 8);
    if (nbeg < nend) {
      int n = nbeg;
      int nextB = poffsets[n + 1];
      const int ebeg = poffsets[nbeg];
      const int eend = poffsets[nend];
      auto ld_pk = [&](int idx) -> unsigned {
        // packed[] has >=20001 words of slack past P; guard the VALUE only.
        const unsigned r = __builtin_nontemporal_load(packed + idx);
        return (idx < eend) ? r : kSent;
      };
      auto rowload = [&](unsigned p) -> u32x4 {
        return *reinterpret_cast<const u32x4*>(
            inp + (long long)(p & 0x7fffu) * kB + cb * 8);
      };
      unsigned pb = ld_pk(ebeg + lane);
      for (int wbase = ebeg; wbase < eend; wbase += 64) {
        const unsigned pbN = ld_pk(wbase + 64 + lane);
        // Phase 1: distribute packed words and ISSUE all 8 row-gathers.
        unsigned pp0 = __shfl(pb, 0 * 8 + g), pp1 = __shfl(pb, 1 * 8 + g);
        unsigned pp2 = __shfl(pb, 2 * 8 + g), pp3 = __shfl(pb, 3 * 8 + g);
        unsigned pp4 = __shfl(pb, 4 * 8 + g), pp5 = __shfl(pb, 5 * 8 + g);
        unsigned pp6 = __shfl(pb, 6 * 8 + g), pp7 = __shfl(pb, 7 * 8 + g);
        u32x4 v0 = rowload(pp0), v1 = rowload(pp1);
        u32x4 v2 = rowload(pp2), v3 = rowload(pp3);
        u32x4 v4 = rowload(pp4), v5 = rowload(pp5);
        u32x4 v6 = rowload(pp6), v7 = rowload(pp7);
        // Phase 2: consume in order with node-flush checks.
#pragma unroll
        for (int j = 0; j < 8; ++j) {
          const int cur = wbase + j * 8;
          if (cur >= eend) break;
          const unsigned pj = (j == 0) ? pp0 : (j == 1) ? pp1 : (j == 2) ? pp2
                            : (j == 3) ? pp3 : (j == 4) ? pp4 : (j == 5) ? pp5
                            : (j == 6) ? pp6 : pp7;
          const u32x4 vj = (j == 0) ? v0 : (j == 1) ? v1 : (j == 2) ? v2
                         : (j == 3) ? v3 : (j == 4) ? v4 : (j == 5) ? v5
                         : (j == 6) ? v6 : v7;
          while (cur >= nextB) { flushNode(n); ++n; nextB = poffsets[n + 1]; }
          const u32x4 w4 =
              *reinterpret_cast<const u32x4*>(wsm + (pj >> 15) * kB + cb * 8);
          const float2 a0 = cvt2(vj.x), a1 = cvt2(vj.y), a2 = cvt2(vj.z),
                       a3 = cvt2(vj.w);
          const float2 b0 = cvt2(w4.x), b1 = cvt2(w4.y), b2 = cvt2(w4.z),
                       b3 = cvt2(w4.w);
          acc[0] += a0.x * b0.x; acc[1] += a0.y * b0.y;
          acc[2] += a1.x * b1.x; acc[3] += a1.y * b1.y;
          acc[4] += a2.x * b2.x; acc[5] += a2.y * b2.y;
          acc[6] += a3.x * b3.x; acc[7] += a3.y * b3.y;
        }
        pb = pbN;
      }
      while (n < nend) { flushNode(n); ++n; }
    }
  }
  // block-level colsum reduce -> one atomic round per block
  if (g == 0) {
#pragma unroll
    for (int j = 0; j < 8; ++j) red[wid][cb * 8 + j] = csum[j];
  }
  __syncthreads();
  if (wid == 0) {
    const float r = red[0][lane] + red[1][lane] + red[2][lane] + red[3][lane];
    unsafeAtomicAdd(&colsum[lane], r);
  }
}

__global__ __launch_bounds__(256) void score_kernel(
    const float* __restrict__ outLast, const float* __restrict__ colsumLast,
    const int* __restrict__ t_index, const int* __restrict__ hr_inverse,
    const float* __restrict__ lin_w, const float* __restrict__ lin_b,
    float* __restrict__ out, int n) {
  const int i = blockIdx.x * blockDim.x + threadIdx.x;
  if (i < n) {
    const int node = t_index[i];
    const int b = hr_inverse[i];
    const float v = outLast[(long long)node * kB + b] / fmaxf(colsumLast[b], kEps);
    out[i] = v * lin_w[0] + lin_b[0];
  }
}

// ---------------- fallback (float-atomic scatter) ----------------

__global__ __launch_bounds__(256) void inp_zero_kernel(
    const float* __restrict__ attnAll, const int* __restrict__ h_set,
    const float* __restrict__ outs, float* __restrict__ inp,
    float* __restrict__ out_next, float* __restrict__ colsum, int step) {
  const long long total = (long long)kN1 * kB;
  for (long long idx = (long long)blockIdx.x * blockDim.x + threadIdx.x; idx < total;
       idx += (long long)gridDim.x * blockDim.x) {
    const int b = (int)(idx & 63);
    const int n = (int)(idx >> 6);
    float acc = (h_set[b] == n) ? attnAll[(step * kNStep) * kB + b] : 0.f;
    for (int t = 1; t <= step; ++t)
      acc += attnAll[(step * kNStep + t) * kB + b] *
             outs[(long long)(t - 1) * kN1 * kB + idx];
    inp[idx] = acc;
    out_next[idx] = 0.f;
  }
  if (blockIdx.x == 0 && threadIdx.x < kB) colsum[threadIdx.x] = 0.f;
}

__global__ __launch_bounds__(256) void scatter_kernel(
    const float* __restrict__ inp, const float* __restrict__ weight,
    const int* __restrict__ nin, const int* __restrict__ nout,
    const int* __restrict__ etype, float* __restrict__ out,
    float* __restrict__ colsum) {
  const int lane = threadIdx.x & 63;
  const int wave = blockIdx.x * (blockDim.x >> 6) + (threadIdx.x >> 6);
  const int nwave = gridDim.x * (blockDim.x >> 6);
  __shared__ float wsm[kNRel2 * kB];
  for (int j = threadIdx.x; j < kNRel2 * kB; j += blockDim.x) wsm[j] = weight[j];
  __syncthreads();
  float csum = 0.f;
  for (int e = wave; e < kNE; e += nwave) {
    const float v = inp[(long long)nin[e] * kB + lane] * wsm[etype[e] * kB + lane];
    unsafeAtomicAdd(&out[(long long)nout[e] * kB + lane], v);
    csum += v;
  }
  unsafeAtomicAdd(&colsum[lane], csum);
}

__global__ __launch_bounds__(256) void normalize_kernel(
    float* __restrict__ out, const float* __restrict__ colsum) {
  const long long total = (long long)kN1 * kB;
  for (long long idx = (long long)blockIdx.x * blockDim.x + threadIdx.x; idx < total;
       idx += (long long)gridDim.x * blockDim.x)
    out[idx] /= fmaxf(colsum[idx & 63], kEps);
}

__global__ __launch_bounds__(256) void score_kernel_norm(
    const float* __restrict__ outLast, const int* __restrict__ t_index,
    const int* __restrict__ hr_inverse, const float* __restrict__ lin_w,
    const float* __restrict__ lin_b, float* __restrict__ out, int n) {
  const int i = blockIdx.x * blockDim.x + threadIdx.x;
  if (i < n) {
    out[i] = outLast[(long long)t_index[i] * kB + hr_inverse[i]] * lin_w[0] + lin_b[0];
  }
}

}  // namespace

extern "C" void kernel_launch(void* const* d_in, const int* in_sizes, int n_in,
                              void* d_out, int out_size, void* d_ws, size_t ws_size,
                              hipStream_t stream) {
  const float* query_emb = (const float*)d_in[0];
  const float* w_ih = (const float*)d_in[1];
  const float* w_hh = (const float*)d_in[2];
  const float* b_ih = (const float*)d_in[3];
  const float* b_hh = (const float*)d_in[4];
  const float* wl_w = (const float*)d_in[5];
  const float* wl_b = (const float*)d_in[6];
  const float* lin_w = (const float*)d_in[7];
  const float* lin_b = (const float*)d_in[8];
  const int* edge_index = (const int*)d_in[9];
  const int* edge_type = (const int*)d_in[10];
  const int* h_set = (const int*)d_in[11];
  const int* r_set = (const int*)d_in[12];
  const int* t_index = (const int*)d_in[13];
  const int* hr_inverse = (const int*)d_in[14];
  float* out = (float*)d_out;

  const int* nin = edge_index;
  const int* nout = edge_index + kNE;

  // ---- workspace layout ----
  float* ws = (float*)d_ws;
  float* hidden = ws;                                   // 6*64*128
  float* attnAll = hidden + kNStep * kB * kHid;         // 6*6*64
  float* weightAll = attnAll + kNStep * kNStep * kB;    // 6*24*64
  float* colsumAll = weightAll + kNStep * kNRel2 * kB;  // 6*64
  float* inpF32 = colsumAll + kNStep * kB;              // kN1*64 f32 slot
  __half* inpH = (__half*)inpF32;                       // (kN1+1)*64 fp16 view
  float* outs = inpF32 + (long long)kN1 * kB;           // 6*kN1*64
  float* tail = outs + (long long)kNStep * kN1 * kB;
  int* counts = (int*)tail;                             // kN1
  int* poffsets = counts + kN1;                         // kN1+1
  int* count2 = poffsets + kN1 + 1;                     // kN1*8 (hist -> cursors)
  int* blockSum = count2 + kN1 * kNXcd;                 // 128
  unsigned* packed = (unsigned*)(blockSum + 128);       // kPMax
  float* wt = (float*)(packed + kPMax);                 // 256*512
  const size_t needed = (size_t)((char*)(wt + 256 * 512) - (char*)d_ws);

  if (ws_size >= needed) {
    transpose_w_kernel<<<512, 256, 0, stream>>>(w_ih, w_hh, wt);
    lstm_fast_kernel<<<kB, 512, 0, stream>>>(query_emb, wt, b_ih, b_hh, r_set, hidden);
    attn_weight_kernel<<<kB, 128, 0, stream>>>(hidden, wl_w, wl_b, attnAll, weightAll);

    zero_kernel<<<(kN1 * kNXcd + 255) / 256, 256, 0, stream>>>(count2, colsumAll);
    hist2_kernel<<<1024, 256, 0, stream>>>(nout, count2);
    scanA_kernel<<<kScanBlocks, 256, 0, stream>>>(count2, counts, blockSum);
    scanB_kernel<<<1, 128, 0, stream>>>(blockSum);
    scanC_kernel<<<kScanBlocks, 256, 0, stream>>>(counts, blockSum, count2, poffsets);
    pad_fill_kernel<<<(kN1 + 255) / 256, 256, 0, stream>>>(poffsets, counts, packed);
    permute_kernel<<<1024, 256, 0, stream>>>(nin, nout, edge_type, count2, packed);

    const int inp_threads = (kN1 + 1) * 16;
    for (int i = 0; i < kNStep; ++i) {
      float* out_i = outs + (long long)i * kN1 * kB;
      inp_kernel<<<(inp_threads + 255) / 256, 256, 0, stream>>>(
          attnAll, colsumAll, h_set, outs, inpH, i);
      gather_seg_kernel<<<kGatherBlocks, 256, 0, stream>>>(
          inpH, weightAll + i * kNRel2 * kB, packed, poffsets, out_i,
          colsumAll + i * kB);
    }
    score_kernel<<<(out_size + 255) / 256, 256, 0, stream>>>(
        outs + 5LL * kN1 * kB, colsumAll + 5 * kB, t_index, hr_inverse, lin_w, lin_b,
        out, out_size);
  } else {
    lstm_kernel<<<kB, 256, 0, stream>>>(query_emb, w_ih, w_hh, b_ih, b_hh, r_set,
                                        hidden);
    attn_weight_kernel<<<kB, 128, 0, stream>>>(hidden, wl_w, wl_b, attnAll, weightAll);
    float* colsum = colsumAll;
    for (int i = 0; i < kNStep; ++i) {
      float* out_i = outs + (long long)i * kN1 * kB;
      inp_zero_kernel<<<2048, 256, 0, stream>>>(attnAll, h_set, outs, inpF32, out_i,
                                                colsum, i);
      scatter_kernel<<<4096, 256, 0, stream>>>(inpF32, weightAll + i * kNRel2 * kB,
                                               nin, nout, edge_type, out_i, colsum);
      normalize_kernel<<<2048, 256, 0, stream>>>(out_i, colsum);
    }
    score_kernel_norm<<<(out_size + 255) / 256, 256, 0, stream>>>(
        outs + 5LL * kN1 * kB, t_index, hr_inverse, lin_w, lin_b, out, out_size);
  }
}